// Round 12
// baseline (1080.759 us; speedup 1.0000x reference)
//
#include <hip/hip_runtime.h>

// ---------------- problem constants ----------------
#define T_LEN 128
// ws layout (bytes)
#define WF_OFF 0            // W frags: 2*8*8*10*64*16 = 1,310,720
#define BI_OFF 1310720      // bias frags: 2*8*8*64*16 = 131,072
#define XZ_OFF 1441792      // xz: 16*128*64*64*2 = 16,777,216
#define HZ_OFF 18219008     // hz: 32*2*64*256*2 = 2,097,152
#define FL_OFF 20316160     // flags: 32*128*4 = 16,384
#define WS_END 20332544
#define SMEM_BYTES 90112    // zbufA 40K | zbufB 40K | htrA 4K | htrB 4K

typedef short bf16x8 __attribute__((ext_vector_type(8)));
typedef float f32x4 __attribute__((ext_vector_type(4)));

#define WAITV0 asm volatile("s_waitcnt vmcnt(0)" ::: "memory")
#define SCHB __builtin_amdgcn_sched_barrier(0)

__device__ __forceinline__ short f32_to_bf16(float f) {
  unsigned u = __float_as_uint(f);
  unsigned r = u + 0x7FFFu + ((u >> 16) & 1u);   // RNE
  return (short)(r >> 16);
}
__device__ __forceinline__ float sigmoidf_fast(float x) {
  return 1.0f / (1.0f + __expf(-x));
}
__device__ __forceinline__ float tanhf_fast(float x) {
  return 1.0f - 2.0f / (__expf(2.0f * x) + 1.0f);
}

// async 16B/lane global->LDS DMA (LDS dest wave-uniform + lane*16)
__device__ __forceinline__ void gll16(const void* g, char* lds_generic) {
  __builtin_amdgcn_global_load_lds(
      (const __attribute__((address_space(1))) void*)g,
      (__attribute__((address_space(3))) void*)lds_generic, 16, 0, 0);
}
// asm-pinned loads (un-sinkable)
__device__ __forceinline__ bf16x8 ald16(const void* p) {
  bf16x8 d;
  asm volatile("global_load_dwordx4 %0, %1, off" : "=v"(d) : "v"(p));
  return d;
}
__device__ __forceinline__ f32x4 aldf4(const void* p) {
  f32x4 d;
  asm volatile("global_load_dwordx4 %0, %1, off" : "=v"(d) : "v"(p));
  return d;
}
// device-scope (coherence point) load/store: bypass per-XCD L2
__device__ __forceinline__ bf16x8 ald16_dev(const void* p) {
  bf16x8 d;
  asm volatile("global_load_dwordx4 %0, %1, off sc0 sc1" : "=v"(d) : "v"(p));
  return d;
}
__device__ __forceinline__ void ast16_dev(void* p, bf16x8 v) {
  asm volatile("global_store_dwordx4 %0, %1, off sc0 sc1" :: "v"(p), "v"(v));
}

// ---------------- prep: pack W (unit-major rows) ----------------
// wf[dir][m][mtl][kt][lane][8 bf16]. WG m owns units [32m,32m+32).
// A-frag: lane row rA = l&15, k = kt*32 + (l>>4)*8 + e.
// torch row for (mtl, rA) = (rA&3)*256 + 32m + 4*mtl + (rA>>2).
__global__ void pack_w(const float* __restrict__ Wih_f, const float* __restrict__ Whh_f,
                       const float* __restrict__ Wih_b, const float* __restrict__ Whh_b,
                       short* __restrict__ wf) {
  int t = blockIdx.x * blockDim.x + threadIdx.x;   // 81920 exact
  int l = t & 63;
  int r1 = t >> 6;          // 1280
  int kt = r1 % 10;
  int r2 = r1 / 10;         // 128
  int mtl = r2 & 7;
  int r3 = r2 >> 3;         // 16
  int m = r3 & 7;
  int dir = r3 >> 3;
  const float* Wih = dir ? Wih_b : Wih_f;
  const float* Whh = dir ? Whh_b : Whh_f;
  int rA = l & 15;
  int row = (rA & 3) * 256 + 32 * m + 4 * mtl + (rA >> 2);
  int kb = kt * 32 + (l >> 4) * 8;
  bf16x8 v;
#pragma unroll
  for (int e = 0; e < 8; ++e) {
    int k = kb + e;
    float f = (k < 64) ? Wih[row * 64 + k] : Whh[row * 256 + (k - 64)];
    v[e] = f32_to_bf16(f);
  }
  long idx = ((((long)dir * 8 + m) * 8 + mtl) * 10 + kt) * 64 + l;
  *reinterpret_cast<bf16x8*>(wf + idx * 8) = v;
}

// bias frag per (dir,m,mtl,lane): f32x4 = gates i,f,g,o of unit 32m+4*mtl+lg
__global__ void pack_bias(const float* __restrict__ bihf, const float* __restrict__ bhhf,
                          const float* __restrict__ bihb, const float* __restrict__ bhhb,
                          float* __restrict__ bp) {
  int t = blockIdx.x * blockDim.x + threadIdx.x;   // 8192 exact
  int l = t & 63;
  int mtl = (t >> 6) & 7;
  int m = (t >> 9) & 7;
  int dir = (t >> 12) & 1;
  const float* bih = dir ? bihb : bihf;
  const float* bhh = dir ? bhhb : bhhf;
  int u = 32 * m + 4 * mtl + ((l >> 4) & 3);
  f32x4 v;
#pragma unroll
  for (int r = 0; r < 4; ++r) v[r] = bih[r * 256 + u] + bhh[r * 256 + u];
  long idx = (((long)dir * 8 + m) * 8 + mtl) * 64 + l;
  *reinterpret_cast<f32x4*>(bp + idx * 4) = v;
}

// xz[s 16][t 128][a 64][c 64] bf16
__global__ void pack_x(const float* __restrict__ x, short* __restrict__ xz) {
  int t = blockIdx.x * blockDim.x + threadIdx.x;   // 2^20 exact
  int cs = t & 7;
  int a  = (t >> 3) & 63;
  int tt = (t >> 9) & 127;
  int s  = (t >> 16) & 15;
  bf16x8 v;
#pragma unroll
  for (int e = 0; e < 8; ++e) {
    int c = cs * 8 + e;
    v[e] = f32_to_bf16(x[(((long)s * 64 + c) * 128 + tt) * 64 + a]);
  }
  long idx = (((long)s * 128 + tt) * 64 + a) * 64 + cs * 8;
  *reinterpret_cast<bf16x8*>(xz + idx) = v;
}

// ---------------- the recurrent kernel ----------------
// grid 128 = s(16, bid&15) x m(8, bid>>4). WG serves TWO groups:
// A = (s, dir0, g=2s), B = (s, dir1, g=2s+1) — independent recurrences,
// phase-interleaved so each group's publish-drain/flag/poll/load latency
// hides under the other group's MFMA+epilogue. Exchange mechanism per group
// is IDENTICAL to R11 (sc0sc1 publish, vmcnt(0) drain, relaxed agent flag,
// sc0sc1 reads; st=0 stages literal zeros). All waits are vmcnt(0) -> any
// compiler spill only over-waits (safe). 1 WG/CU (90KB LDS), 128 WGs
// co-resident.
__global__ __launch_bounds__(512) void lstm_rec(
    const short* __restrict__ wf, const float* __restrict__ bp,
    const short* __restrict__ xz, short* __restrict__ hz,
    int* __restrict__ flags, float* __restrict__ out) {
  extern __shared__ char smem[];
  char* const zbA = smem;            // 40 frags x 1KB
  char* const zbB = smem + 40960;
  char* const htA = smem + 81920;    // [a 64][u_l 32] bf16
  char* const htB = smem + 86016;

  const int bid = blockIdx.x;
  const int m = bid >> 4, s = bid & 15;
  const int tid = threadIdx.x;
  const int w = tid >> 6, l = tid & 63;
  const int lg = l >> 4, ln = l & 15;

  // ---- prologue: pin W for both dirs (20 frags = 80 VGPR) + biases ----
  const char* wA = (const char*)wf + (((long)0 * 8 + m) * 8 + w) * 10 * 1024 + (long)l * 16;
  const char* wB = (const char*)wf + (((long)1 * 8 + m) * 8 + w) * 10 * 1024 + (long)l * 16;
  bf16x8 WA[10], WB[10];
#pragma unroll
  for (int kt = 0; kt < 10; ++kt) {
    WA[kt] = ald16(wA + kt * 1024);
    WB[kt] = ald16(wB + kt * 1024);
  }
  const f32x4 biasA = aldf4((const char*)bp +
      ((((long)0 * 8 + m) * 8 + w) * 64 + l) * 16);
  const f32x4 biasB = aldf4((const char*)bp +
      ((((long)1 * 8 + m) * 8 + w) * 64 + l) * 16);
  WAITV0;

  const char* xzb = (const char*)xz + (long)s * (128L * 64 * 64 * 2);
  char* const hzA = (char*)hz + (long)(2 * s) * 65536;
  char* const hzB = (char*)hz + (long)(2 * s + 1) * 65536;
  int* const flgA = flags + (2 * s) * T_LEN;
  int* const flgB = flags + (2 * s + 1) * T_LEN;

  float cstA[4] = {0.f, 0.f, 0.f, 0.f};
  float cstB[4] = {0.f, 0.f, 0.f, 0.f};

  // stage zbufA for st=0: x(t=0) via gll16, h = zeros
  {
    const char* xstep = xzb;   // t=0
    const int kt = w >> 2, nt = w & 3;
    gll16(xstep + (long)(((nt * 16 + ln) * 64 + kt * 32 + lg * 8) * 2),
          zbA + w * 1024);
    bf16x8 z8 = (bf16x8)(short)0;
#pragma unroll
    for (int j = 0; j < 4; ++j)
      *reinterpret_cast<bf16x8*>(zbA + (8 + 4 * w + j) * 1024 + l * 16) = z8;
  }
  WAITV0;
  __syncthreads();

  // per-group compute phase: MFMA + epilogue + htr + out
#define COMPUTE(ZB, HT, W_, BIAS, CST, T_, DIRQ) do {                         \
    f32x4 acc[4];                                                             \
    _Pragma("unroll")                                                         \
    for (int nt = 0; nt < 4; ++nt) acc[nt] = (BIAS);                          \
    _Pragma("unroll")                                                         \
    for (int kt = 0; kt < 10; ++kt)                                           \
      _Pragma("unroll")                                                       \
      for (int nt = 0; nt < 4; ++nt) {                                        \
        bf16x8 b = *reinterpret_cast<const bf16x8*>(                          \
            (ZB) + (kt * 4 + nt) * 1024 + l * 16);                            \
        acc[nt] = __builtin_amdgcn_mfma_f32_16x16x32_bf16(W_[kt], b, acc[nt], 0, 0, 0); \
      }                                                                       \
    float hv[4];                                                              \
    _Pragma("unroll")                                                         \
    for (int nt = 0; nt < 4; ++nt) {                                          \
      float gi = sigmoidf_fast(acc[nt][0]);                                   \
      float gf = sigmoidf_fast(acc[nt][1]);                                   \
      float gg = tanhf_fast(acc[nt][2]);                                      \
      float go = sigmoidf_fast(acc[nt][3]);                                   \
      float cc = gf * (CST)[nt] + gi * gg;                                    \
      (CST)[nt] = cc;                                                         \
      hv[nt] = go * tanhf_fast(cc);                                           \
    }                                                                         \
    _Pragma("unroll")                                                         \
    for (int nt = 0; nt < 4; ++nt)                                            \
      *reinterpret_cast<short*>((HT) + (nt * 16 + ln) * 64 + (4 * w + lg) * 2) = \
          f32_to_bf16(hv[nt]);                                                \
    {                                                                         \
      const long hrow = (long)(DIRQ) * 256 + 32 * m + 4 * w + lg;             \
      _Pragma("unroll")                                                       \
      for (int nt = 0; nt < 4; ++nt) {                                        \
        const int a = nt * 16 + ln;                                           \
        out[(((long)s * 512 + hrow) * 128 + (T_)) * 64 + a] = hv[nt];         \
      }                                                                       \
    }                                                                         \
  } while (0)

  // per-group publish phase (after barrier ensuring htr complete)
#define PUBLISH(HT, HZ, ST) do {                                              \
    if (tid < 256) {                                                          \
      const int a = tid >> 2, seg = tid & 3;                                  \
      bf16x8 v = *reinterpret_cast<const bf16x8*>((HT) + tid * 16);           \
      ast16_dev((HZ) + (long)((ST) & 1) * 32768 +                             \
                (long)((a * 256 + 32 * m + seg * 8) * 2), v);                 \
    }                                                                         \
  } while (0)

  for (int st = 0; st < T_LEN; ++st) {
    const int tA = st, tB = T_LEN - 1 - st;

    // ======== A compute (zbA staged) ========
    COMPUTE(zbA, htA, WA, biasA, cstA, tA, 0);
    __syncthreads();                     // htA complete
    // ======== A publish (no wait yet) ========
    PUBLISH(htA, hzA, st);

    // ======== B stage (hides A publish drain) ========
    {
      const char* xstep = xzb + (long)tB * 8192;
      const int kt = w >> 2, nt = w & 3;
      gll16(xstep + (long)(((nt * 16 + ln) * 64 + kt * 32 + lg * 8) * 2),
            zbB + w * 1024);
      bf16x8 hstg[4];
      if (st == 0) {
#pragma unroll
        for (int j = 0; j < 4; ++j) hstg[j] = (bf16x8)(short)0;
      } else {
        // all-wave poll (coalesced single-address load per wave)
        while (__hip_atomic_load(flgB + st - 1, __ATOMIC_RELAXED,
                                 __HIP_MEMORY_SCOPE_AGENT) < 8)
          __builtin_amdgcn_s_sleep(2);
        const char* hprev = hzB + (long)((st + 1) & 1) * 32768;
#pragma unroll
        for (int j = 0; j < 4; ++j)
          hstg[j] = ald16_dev(
              hprev + (long)(((j * 16 + ln) * 256 + w * 32 + lg * 8) * 2));
      }
      WAITV0; SCHB;                      // drains A-publish + outA + xB + hB
      __syncthreads();                   // all waves drained
      if (tid == 0)
        __hip_atomic_fetch_add(flgA + st, 1, __ATOMIC_RELAXED,
                               __HIP_MEMORY_SCOPE_AGENT);
#pragma unroll
      for (int j = 0; j < 4; ++j)
        *reinterpret_cast<bf16x8*>(zbB + (8 + 4 * w + j) * 1024 + l * 16) = hstg[j];
    }
    __syncthreads();                     // zbB ready

    // ======== B compute ========
    COMPUTE(zbB, htB, WB, biasB, cstB, tB, 1);
    __syncthreads();                     // htB complete
    // ======== B publish ========
    PUBLISH(htB, hzB, st);

    // ======== A stage for st+1 (hides B publish drain) ========
    {
      const int tA1 = (st < T_LEN - 1) ? st + 1 : st;
      const char* xstep = xzb + (long)tA1 * 8192;
      const int kt = w >> 2, nt = w & 3;
      gll16(xstep + (long)(((nt * 16 + ln) * 64 + kt * 32 + lg * 8) * 2),
            zbA + w * 1024);
      while (__hip_atomic_load(flgA + st, __ATOMIC_RELAXED,
                               __HIP_MEMORY_SCOPE_AGENT) < 8)
        __builtin_amdgcn_s_sleep(2);
      const char* hprev = hzA + (long)(st & 1) * 32768;
      bf16x8 hstg[4];
#pragma unroll
      for (int j = 0; j < 4; ++j)
        hstg[j] = ald16_dev(
            hprev + (long)(((j * 16 + ln) * 256 + w * 32 + lg * 8) * 2));
      WAITV0; SCHB;                      // drains B-publish + outB + xA + hA
      __syncthreads();
      if (tid == 0)
        __hip_atomic_fetch_add(flgB + st, 1, __ATOMIC_RELAXED,
                               __HIP_MEMORY_SCOPE_AGENT);
#pragma unroll
      for (int j = 0; j < 4; ++j)
        *reinterpret_cast<bf16x8*>(zbA + (8 + 4 * w + j) * 1024 + l * 16) = hstg[j];
    }
    __syncthreads();                     // zbA ready for st+1
  }
#undef COMPUTE
#undef PUBLISH
}

// ---------------- launcher ----------------
extern "C" void kernel_launch(void* const* d_in, const int* in_sizes, int n_in,
                              void* d_out, int out_size, void* d_ws, size_t ws_size,
                              hipStream_t stream) {
  const float* x     = (const float*)d_in[0];
  const float* Wih_f = (const float*)d_in[1];
  const float* Whh_f = (const float*)d_in[2];
  const float* bih_f = (const float*)d_in[3];
  const float* bhh_f = (const float*)d_in[4];
  const float* Wih_b = (const float*)d_in[5];
  const float* Whh_b = (const float*)d_in[6];
  const float* bih_b = (const float*)d_in[7];
  const float* bhh_b = (const float*)d_in[8];
  float* out = (float*)d_out;

  char* ws = (char*)d_ws;
  short* wf    = (short*)(ws + WF_OFF);
  float* bp    = (float*)(ws + BI_OFF);
  short* xz    = (short*)(ws + XZ_OFF);
  short* hz    = (short*)(ws + HZ_OFF);
  int*   flags = (int*)(ws + FL_OFF);

  static int smem_set = 0;
  if (!smem_set) {
    (void)hipFuncSetAttribute((const void*)lstm_rec,
                              hipFuncAttributeMaxDynamicSharedMemorySize, SMEM_BYTES);
    smem_set = 1;
  }

  hipLaunchKernelGGL(pack_w, dim3(320), dim3(256), 0, stream,
                     Wih_f, Whh_f, Wih_b, Whh_b, wf);
  hipLaunchKernelGGL(pack_bias, dim3(32), dim3(256), 0, stream,
                     bih_f, bhh_f, bih_b, bhh_b, bp);
  hipLaunchKernelGGL(pack_x, dim3(4096), dim3(256), 0, stream, x, xz);
  // zero flags only (hz is write-before-read; st=0 stages literal zeros)
  hipMemsetAsync(ws + FL_OFF, 0, WS_END - FL_OFF, stream);
  hipLaunchKernelGGL(lstm_rec, dim3(128), dim3(512), SMEM_BYTES, stream,
                     wf, bp, xz, hz, flags, out);
}

// Round 13
// 519.969 us; speedup vs baseline: 2.0785x; 2.0785x over previous
//
#include <hip/hip_runtime.h>

// ---------------- problem constants ----------------
#define T_LEN 128
// ws layout (bytes)
#define WF_OFF 0            // W frags: 2*4*16*10*64*16 = 1,310,720
#define BI_OFF 1310720      // bias frags: 2*4*16*64*16 = 131,072
#define XZ_OFF 1441792      // xz: 16*128*64*64*2 = 16,777,216
#define HZ_OFF 18219008     // hz: 32*2*64*256*2 = 2,097,152
#define FL_OFF 20316160     // flags: 32*2*128*4 = 32,768
#define WS_END 20348928

typedef short bf16x8 __attribute__((ext_vector_type(8)));
typedef float f32x4 __attribute__((ext_vector_type(4)));

#define WAITV0 asm volatile("s_waitcnt vmcnt(0)" ::: "memory")
#define SCHB __builtin_amdgcn_sched_barrier(0)

__device__ __forceinline__ short f32_to_bf16(float f) {
  unsigned u = __float_as_uint(f);
  unsigned r = u + 0x7FFFu + ((u >> 16) & 1u);   // RNE
  return (short)(r >> 16);
}
__device__ __forceinline__ float sigmoidf_fast(float x) {
  return 1.0f / (1.0f + __expf(-x));
}
__device__ __forceinline__ float tanhf_fast(float x) {
  return 1.0f - 2.0f / (__expf(2.0f * x) + 1.0f);
}

// async 16B/lane global->LDS DMA (LDS dest wave-uniform + lane*16)
__device__ __forceinline__ void gll16(const void* g, char* lds_generic) {
  __builtin_amdgcn_global_load_lds(
      (const __attribute__((address_space(1))) void*)g,
      (__attribute__((address_space(3))) void*)lds_generic, 16, 0, 0);
}
// asm-pinned loads (un-sinkable)
__device__ __forceinline__ bf16x8 ald16(const void* p) {
  bf16x8 d;
  asm volatile("global_load_dwordx4 %0, %1, off" : "=v"(d) : "v"(p));
  return d;
}
__device__ __forceinline__ f32x4 aldf4(const void* p) {
  f32x4 d;
  asm volatile("global_load_dwordx4 %0, %1, off" : "=v"(d) : "v"(p));
  return d;
}
// device-scope (coherence point) load/store: bypass per-XCD L2
__device__ __forceinline__ bf16x8 ald16_dev(const void* p) {
  bf16x8 d;
  asm volatile("global_load_dwordx4 %0, %1, off sc0 sc1" : "=v"(d) : "v"(p));
  return d;
}
__device__ __forceinline__ void ast16_dev(void* p, bf16x8 v) {
  asm volatile("global_store_dwordx4 %0, %1, off sc0 sc1" :: "v"(p), "v"(v));
}

// ---------------- prep: pack W (unit-major rows, 2-D partition) ----------
// wf[dir][p][mtw 16][kt 10][lane]. WG (p,q) owns units [64p, 64p+64).
// A-frag: lane row rA = l&15, k = kt*32 + (l>>4)*8 + e.
// torch row for (p, mtw, rA) = (rA&3)*256 + 64p + 4*mtw + (rA>>2)
// (gate = rA&3 in i,f,g,o order; unit_local = 4*mtw + rA>>2, 0..63).
__global__ void pack_w(const float* __restrict__ Wih_f, const float* __restrict__ Whh_f,
                       const float* __restrict__ Wih_b, const float* __restrict__ Whh_b,
                       short* __restrict__ wf) {
  int t = blockIdx.x * blockDim.x + threadIdx.x;   // 81920 exact
  int l = t & 63;
  int r1 = t >> 6;          // 1280
  int kt = r1 % 10;
  int r2 = r1 / 10;         // 128
  int mtw = r2 & 15;
  int r3 = r2 >> 4;         // 8
  int p = r3 & 3;
  int dir = r3 >> 2;
  const float* Wih = dir ? Wih_b : Wih_f;
  const float* Whh = dir ? Whh_b : Whh_f;
  int rA = l & 15;
  int row = (rA & 3) * 256 + 64 * p + 4 * mtw + (rA >> 2);
  int kb = kt * 32 + (l >> 4) * 8;
  bf16x8 v;
#pragma unroll
  for (int e = 0; e < 8; ++e) {
    int k = kb + e;
    float f = (k < 64) ? Wih[row * 64 + k] : Whh[row * 256 + (k - 64)];
    v[e] = f32_to_bf16(f);
  }
  long idx = ((((long)dir * 4 + p) * 16 + mtw) * 10 + kt) * 64 + l;
  *reinterpret_cast<bf16x8*>(wf + idx * 8) = v;
}

// bias frag per (dir,p,mtw,lane): f32x4 = gates i,f,g,o of unit 64p+4*mtw+lg
__global__ void pack_bias(const float* __restrict__ bihf, const float* __restrict__ bhhf,
                          const float* __restrict__ bihb, const float* __restrict__ bhhb,
                          float* __restrict__ bp) {
  int t = blockIdx.x * blockDim.x + threadIdx.x;   // 8192 exact
  int l = t & 63;
  int mtw = (t >> 6) & 15;
  int p = (t >> 10) & 3;
  int dir = (t >> 12) & 1;
  const float* bih = dir ? bihb : bihf;
  const float* bhh = dir ? bhhb : bhhf;
  int u = 64 * p + 4 * mtw + ((l >> 4) & 3);
  f32x4 v;
#pragma unroll
  for (int r = 0; r < 4; ++r) v[r] = bih[r * 256 + u] + bhh[r * 256 + u];
  long idx = (((long)dir * 4 + p) * 16 + mtw) * 64 + l;
  *reinterpret_cast<f32x4*>(bp + idx * 4) = v;
}

// xz[s 16][t 128][a 64][c 64] bf16  (unchanged from R11)
__global__ void pack_x(const float* __restrict__ x, short* __restrict__ xz) {
  int t = blockIdx.x * blockDim.x + threadIdx.x;   // 2^20 exact
  int cs = t & 7;
  int a  = (t >> 3) & 63;
  int tt = (t >> 9) & 127;
  int s  = (t >> 16) & 15;
  bf16x8 v;
#pragma unroll
  for (int e = 0; e < 8; ++e) {
    int c = cs * 8 + e;
    v[e] = f32_to_bf16(x[(((long)s * 64 + c) * 128 + tt) * 64 + a]);
  }
  long idx = (((long)s * 128 + tt) * 64 + a) * 64 + cs * 8;
  *reinterpret_cast<bf16x8*>(xz + idx) = v;
}

// ---------------- the recurrent kernel ----------------
// grid 256: g = bid&31 (group: dir = g&1, sample s = g>>1; bid%8 keeps a
// group's WGs XCD-aligned if round-robin holds — locality only), r = bid>>5:
// q = r&1 (batch-block, 32 rows), p = r>>1 (unit-block, 64 units).
// WG owns 64 units x 32 batch. h-exchange partners = the 4 WGs {p'=0..3, q}
// (was 8 in R11 -> max-of-4 skew). Protocol VERBATIM from R11: sc0sc1
// publish -> vmcnt(0) -> barrier -> relaxed agent flag; consumers all-wave
// poll -> sc0sc1 reads -> ds_write -> barrier. st=0 stages literal zeros
// (hz never memset). Out stores AFTER flag post (off the pre-flag drain).
// All waits vmcnt(0): compiler spills only over-wait (safe).
__global__ __launch_bounds__(512) void lstm_rec(
    const short* __restrict__ wf, const float* __restrict__ bp,
    const short* __restrict__ xz, short* __restrict__ hz,
    int* __restrict__ flags, float* __restrict__ out) {
  __shared__ __align__(16) char zbuf[20480];   // 20 frags x 1KB (f = kt*2+nt)
  __shared__ __align__(16) char htr[4096];     // [a_l 32][u_l 64] bf16

  const int bid = blockIdx.x;
  const int g = bid & 31, r = bid >> 5;
  const int q = r & 1, p = r >> 1;
  const int dir = g & 1, s = g >> 1;
  const int tid = threadIdx.x;
  const int w = tid >> 6, l = tid & 63;
  const int lg = l >> 4, ln = l & 15;

  // ---- prologue: pin W (2 mt x 10 kt = 80 VGPR) + bias via asm loads ----
  const char* wbase = (const char*)wf +
      ((((long)dir * 4 + p) * 16 + 2 * w) * 10) * 1024 + (long)l * 16;
  bf16x8 W[2][10];
#pragma unroll
  for (int mtid = 0; mtid < 2; ++mtid)
#pragma unroll
    for (int kt = 0; kt < 10; ++kt)
      W[mtid][kt] = ald16(wbase + (mtid * 10 + kt) * 1024);
  f32x4 biasv[2];
#pragma unroll
  for (int mtid = 0; mtid < 2; ++mtid)
    biasv[mtid] = aldf4((const char*)bp +
        (((((long)dir * 4 + p) * 16 + 2 * w + mtid) * 64 + l) * 16));
  WAITV0;

  const char* xzb = (const char*)xz + (long)s * (128L * 64 * 64 * 2);
  char* const hzg = (char*)hz + (long)g * 65536;
  int* const flg = flags + (g * 2 + q) * T_LEN;

  float cst[2][2] = {{0.f, 0.f}, {0.f, 0.f}};

  for (int st = 0; st < T_LEN; ++st) {
    const int t = dir ? (T_LEN - 1 - st) : st;

    // ---- stage x (waves 0-3, one frag each; flies during poll) ----
    {
      const char* xstep = xzb + (long)t * 8192;
      if (w < 4) {
        const int kt = w >> 1, nt = w & 1;
        gll16(xstep + (long)(((32 * q + nt * 16 + ln) * 64 + kt * 32 + lg * 8) * 2),
              zbuf + w * 1024);
      }
    }

    // ---- poll partners' h(st-1) (all-wave; gates each wave's own reads) ----
    if (st > 0) {
      while (__hip_atomic_load(flg + (st - 1), __ATOMIC_RELAXED,
                               __HIP_MEMORY_SCOPE_AGENT) < 4)
        __builtin_amdgcn_s_sleep(2);
    }

    // ---- h reads: 2 frags/wave (f = 4+2w+j; kt = f>>1, nt = f&1) ----
    {
      bf16x8 hstg[2];
      if (st == 0) {
#pragma unroll
        for (int j = 0; j < 2; ++j) hstg[j] = (bf16x8)(short)0;
      } else {
        const char* hprev = hzg + (long)((st + 1) & 1) * 32768;
#pragma unroll
        for (int j = 0; j < 2; ++j) {
          const int f = 4 + 2 * w + j, kt = f >> 1, nt = f & 1;
          hstg[j] = ald16_dev(hprev +
              (long)(((32 * q + nt * 16 + ln) * 256 + (kt - 2) * 32 + lg * 8) * 2));
        }
      }
      WAITV0; SCHB;
#pragma unroll
      for (int j = 0; j < 2; ++j)
        *reinterpret_cast<bf16x8*>(zbuf + (4 + 2 * w + j) * 1024 + l * 16) = hstg[j];
    }
    __syncthreads();   // (1) z staged

    // ---- MFMA: 10 kt x 2 nt x 2 mt, W pinned, B from LDS ----
    f32x4 acc[2][2];
#pragma unroll
    for (int mtid = 0; mtid < 2; ++mtid)
#pragma unroll
      for (int nt = 0; nt < 2; ++nt) acc[mtid][nt] = biasv[mtid];
#pragma unroll
    for (int kt = 0; kt < 10; ++kt)
#pragma unroll
      for (int nt = 0; nt < 2; ++nt) {
        bf16x8 b = *reinterpret_cast<const bf16x8*>(
            zbuf + (kt * 2 + nt) * 1024 + l * 16);
        acc[0][nt] = __builtin_amdgcn_mfma_f32_16x16x32_bf16(W[0][kt], b, acc[0][nt], 0, 0, 0);
        acc[1][nt] = __builtin_amdgcn_mfma_f32_16x16x32_bf16(W[1][kt], b, acc[1][nt], 0, 0, 0);
      }

    // ---- epilogue (lane-local: regs 0..3 = gates i,f,g,o) ----
    float hv[2][2];
#pragma unroll
    for (int mtid = 0; mtid < 2; ++mtid)
#pragma unroll
      for (int nt = 0; nt < 2; ++nt) {
        float gi = sigmoidf_fast(acc[mtid][nt][0]);
        float gf = sigmoidf_fast(acc[mtid][nt][1]);
        float gg = tanhf_fast(acc[mtid][nt][2]);
        float go = sigmoidf_fast(acc[mtid][nt][3]);
        float cc = gf * cst[mtid][nt] + gi * gg;
        cst[mtid][nt] = cc;
        hv[mtid][nt] = go * tanhf_fast(cc);
      }
#pragma unroll
    for (int mtid = 0; mtid < 2; ++mtid)
#pragma unroll
      for (int nt = 0; nt < 2; ++nt)
        *reinterpret_cast<short*>(htr +
            ((nt * 16 + ln) * 64 + 8 * w + 4 * mtid + lg) * 2) =
            f32_to_bf16(hv[mtid][nt]);
    __syncthreads();   // (2) htr complete

    // ---- publish h rectangle (sc0sc1; 4KB = 256 x 16B) ----
    {
      char* hcur = hzg + (long)(st & 1) * 32768;
      if (tid < 256) {
        const int a_l = tid >> 3, seg = tid & 7;
        bf16x8 v = *reinterpret_cast<const bf16x8*>(htr + tid * 16);
        ast16_dev(hcur + (long)(((32 * q + a_l) * 256 + 64 * p + seg * 8) * 2), v);
      }
    }
    WAITV0;            // publish at coherence point
    __syncthreads();   // (3) all waves drained; also orders MFMA reads
                       //     before next step's zbuf overwrites
    if (tid == 0)
      __hip_atomic_fetch_add(flg + st, 1, __ATOMIC_RELAXED,
                             __HIP_MEMORY_SCOPE_AGENT);

    // ---- out stores (after flag; overlap next step's poll) ----
    {
#pragma unroll
      for (int mtid = 0; mtid < 2; ++mtid)
#pragma unroll
        for (int nt = 0; nt < 2; ++nt) {
          const long u = 64 * p + 8 * w + 4 * mtid + lg;
          const int a = 32 * q + nt * 16 + ln;
          out[(((long)s * 512 + dir * 256 + u) * 128 + t) * 64 + a] = hv[mtid][nt];
        }
    }
  }
}

// ---------------- launcher ----------------
extern "C" void kernel_launch(void* const* d_in, const int* in_sizes, int n_in,
                              void* d_out, int out_size, void* d_ws, size_t ws_size,
                              hipStream_t stream) {
  const float* x     = (const float*)d_in[0];
  const float* Wih_f = (const float*)d_in[1];
  const float* Whh_f = (const float*)d_in[2];
  const float* bih_f = (const float*)d_in[3];
  const float* bhh_f = (const float*)d_in[4];
  const float* Wih_b = (const float*)d_in[5];
  const float* Whh_b = (const float*)d_in[6];
  const float* bih_b = (const float*)d_in[7];
  const float* bhh_b = (const float*)d_in[8];
  float* out = (float*)d_out;

  char* ws = (char*)d_ws;
  short* wf    = (short*)(ws + WF_OFF);
  float* bp    = (float*)(ws + BI_OFF);
  short* xz    = (short*)(ws + XZ_OFF);
  short* hz    = (short*)(ws + HZ_OFF);
  int*   flags = (int*)(ws + FL_OFF);

  hipLaunchKernelGGL(pack_w, dim3(320), dim3(256), 0, stream,
                     Wih_f, Whh_f, Wih_b, Whh_b, wf);
  hipLaunchKernelGGL(pack_bias, dim3(32), dim3(256), 0, stream,
                     bih_f, bhh_f, bih_b, bhh_b, bp);
  hipLaunchKernelGGL(pack_x, dim3(4096), dim3(256), 0, stream, x, xz);
  // zero flags only (hz is write-before-read; st=0 stages literal zeros)
  hipMemsetAsync(ws + FL_OFF, 0, WS_END - FL_OFF, stream);
  hipLaunchKernelGGL(lstm_rec, dim3(256), dim3(512), 0, stream,
                     wf, bp, xz, hz, flags, out);
}

// Round 16
// 517.222 us; speedup vs baseline: 2.0895x; 1.0053x over previous
//
#include <hip/hip_runtime.h>

// ---------------- problem constants ----------------
#define T_LEN 128
// ws layout (bytes) — identical to R13
#define WF_OFF 0            // W frags: 2*4*16*10*64*16 = 1,310,720
#define BI_OFF 1310720      // bias frags: 2*4*16*64*16 = 131,072
#define XZ_OFF 1441792      // xz: 16*128*64*64*2 = 16,777,216
#define HZ_OFF 18219008     // hz: 32*2*64*256*2 = 2,097,152
#define FL_OFF 20316160     // flags: 32*2*128*4 = 32,768
#define WS_END 20348928

typedef short bf16x8 __attribute__((ext_vector_type(8)));
typedef float f32x4 __attribute__((ext_vector_type(4)));

#define WAITV0 asm volatile("s_waitcnt vmcnt(0)" ::: "memory")
#define SCHB __builtin_amdgcn_sched_barrier(0)

__device__ __forceinline__ short f32_to_bf16(float f) {
  unsigned u = __float_as_uint(f);
  unsigned r = u + 0x7FFFu + ((u >> 16) & 1u);   // RNE
  return (short)(r >> 16);
}
__device__ __forceinline__ float sigmoidf_fast(float x) {
  return 1.0f / (1.0f + __expf(-x));
}
__device__ __forceinline__ float tanhf_fast(float x) {
  return 1.0f - 2.0f / (__expf(2.0f * x) + 1.0f);
}

// async 16B/lane global->LDS DMA (LDS dest wave-uniform + lane*16)
__device__ __forceinline__ void gll16(const void* g, char* lds_generic) {
  __builtin_amdgcn_global_load_lds(
      (const __attribute__((address_space(1))) void*)g,
      (__attribute__((address_space(3))) void*)lds_generic, 16, 0, 0);
}
// asm-pinned plain loads (prologue W/bias)
__device__ __forceinline__ bf16x8 ald16(const void* p) {
  bf16x8 d;
  asm volatile("global_load_dwordx4 %0, %1, off" : "=v"(d) : "v"(p));
  return d;
}
__device__ __forceinline__ f32x4 aldf4(const void* p) {
  f32x4 d;
  asm volatile("global_load_dwordx4 %0, %1, off" : "=v"(d) : "v"(p));
  return d;
}
// device-scope (coherence point) DATA ops — R13-proven. SYNC SIGNALS must be
// atomics (R14/R15 lesson: plain-store stamp + raw-load spin deadlocks).
__device__ __forceinline__ bf16x8 ald16_dev(const void* p) {
  bf16x8 d;
  asm volatile("global_load_dwordx4 %0, %1, off sc0 sc1" : "=v"(d) : "v"(p));
  return d;
}
__device__ __forceinline__ void ast16_dev(void* p, bf16x8 v) {
  asm volatile("global_store_dwordx4 %0, %1, off sc0 sc1" :: "v"(p), "v"(v));
}

// ---------------- prep: pack W (unit-major rows, 2-D partition) ----------
// wf[dir][p][mtw 16][kt 10][lane]. WG (p,q) owns units [64p, 64p+64).
// A-frag: lane row rA = l&15, k = kt*32 + (l>>4)*8 + e.
// torch row for (p, mtw, rA) = (rA&3)*256 + 64p + 4*mtw + (rA>>2).
__global__ void pack_w(const float* __restrict__ Wih_f, const float* __restrict__ Whh_f,
                       const float* __restrict__ Wih_b, const float* __restrict__ Whh_b,
                       short* __restrict__ wf) {
  int t = blockIdx.x * blockDim.x + threadIdx.x;   // 81920 exact
  int l = t & 63;
  int r1 = t >> 6;          // 1280
  int kt = r1 % 10;
  int r2 = r1 / 10;         // 128
  int mtw = r2 & 15;
  int r3 = r2 >> 4;         // 8
  int p = r3 & 3;
  int dir = r3 >> 2;
  const float* Wih = dir ? Wih_b : Wih_f;
  const float* Whh = dir ? Whh_b : Whh_f;
  int rA = l & 15;
  int row = (rA & 3) * 256 + 64 * p + 4 * mtw + (rA >> 2);
  int kb = kt * 32 + (l >> 4) * 8;
  bf16x8 v;
#pragma unroll
  for (int e = 0; e < 8; ++e) {
    int k = kb + e;
    float f = (k < 64) ? Wih[row * 64 + k] : Whh[row * 256 + (k - 64)];
    v[e] = f32_to_bf16(f);
  }
  long idx = ((((long)dir * 4 + p) * 16 + mtw) * 10 + kt) * 64 + l;
  *reinterpret_cast<bf16x8*>(wf + idx * 8) = v;
}

// bias frag per (dir,p,mtw,lane): f32x4 = gates i,f,g,o of unit 64p+4*mtw+lg
__global__ void pack_bias(const float* __restrict__ bihf, const float* __restrict__ bhhf,
                          const float* __restrict__ bihb, const float* __restrict__ bhhb,
                          float* __restrict__ bp) {
  int t = blockIdx.x * blockDim.x + threadIdx.x;   // 8192 exact
  int l = t & 63;
  int mtw = (t >> 6) & 15;
  int p = (t >> 10) & 3;
  int dir = (t >> 12) & 1;
  const float* bih = dir ? bihb : bihf;
  const float* bhh = dir ? bhhb : bhhf;
  int u = 64 * p + 4 * mtw + ((l >> 4) & 3);
  f32x4 v;
#pragma unroll
  for (int r = 0; r < 4; ++r) v[r] = bih[r * 256 + u] + bhh[r * 256 + u];
  long idx = (((long)dir * 4 + p) * 16 + mtw) * 64 + l;
  *reinterpret_cast<f32x4*>(bp + idx * 4) = v;
}

// xz[s 16][t 128][a 64][c 64] bf16
__global__ void pack_x(const float* __restrict__ x, short* __restrict__ xz) {
  int t = blockIdx.x * blockDim.x + threadIdx.x;   // 2^20 exact
  int cs = t & 7;
  int a  = (t >> 3) & 63;
  int tt = (t >> 9) & 127;
  int s  = (t >> 16) & 15;
  bf16x8 v;
#pragma unroll
  for (int e = 0; e < 8; ++e) {
    int c = cs * 8 + e;
    v[e] = f32_to_bf16(x[(((long)s * 64 + c) * 128 + tt) * 64 + a]);
  }
  long idx = (((long)s * 128 + tt) * 64 + a) * 64 + cs * 8;
  *reinterpret_cast<bf16x8*>(xz + idx) = v;
}

// ---------------- the recurrent kernel ----------------
// grid 256: g = bid&31 (dir = g&1, sample s = g>>1), r = bid>>5: q = r&1
// (batch-block, 32 rows), p = r>>1 (unit-block, 64 units). Exchange clique =
// {(p',q), p'=0..3}. Sync protocol = R13 VERBATIM (atomicAdd flag post +
// __hip_atomic_load relaxed-agent spin; sc0sc1 h publish/read; literal-zero
// st0). Two local-only upgrades vs R13: (1) x-projection (kt0,1) computed
// during the poll window (pure reordering; K-order per output element
// unchanged: bias, kt0,1, kt2..9 -> absmax bit-identical); (2) htr rows
// padded to 72 shorts (16-way -> ~4-way LDS write conflicts).
__global__ __launch_bounds__(512) void lstm_rec(
    const short* __restrict__ wf, const float* __restrict__ bp,
    const short* __restrict__ xz, short* __restrict__ hz,
    int* __restrict__ flags, float* __restrict__ out) {
  __shared__ __align__(16) char zbuf[20480];   // 20 frags x 1KB (f = kt*2+nt)
  __shared__ __align__(16) char htr[4608];     // [a_l 32] rows x 72 shorts

  const int bid = blockIdx.x;
  const int g = bid & 31, r = bid >> 5;
  const int q = r & 1, p = r >> 1;
  const int dir = g & 1, s = g >> 1;
  const int tid = threadIdx.x;
  const int w = tid >> 6, l = tid & 63;
  const int lg = l >> 4, ln = l & 15;

  // ---- prologue: pin W (2 mt x 10 kt = 80 VGPR) + bias via asm loads ----
  const char* wbase = (const char*)wf +
      ((((long)dir * 4 + p) * 16 + 2 * w) * 10) * 1024 + (long)l * 16;
  bf16x8 W[2][10];
#pragma unroll
  for (int mtid = 0; mtid < 2; ++mtid)
#pragma unroll
    for (int kt = 0; kt < 10; ++kt)
      W[mtid][kt] = ald16(wbase + (mtid * 10 + kt) * 1024);
  f32x4 biasv[2];
#pragma unroll
  for (int mtid = 0; mtid < 2; ++mtid)
    biasv[mtid] = aldf4((const char*)bp +
        (((((long)dir * 4 + p) * 16 + 2 * w + mtid) * 64 + l) * 16));
  WAITV0;

  const char* xzb = (const char*)xz + (long)s * (128L * 64 * 64 * 2);
  char* const hzg = (char*)hz + (long)g * 65536;
  int* const flg = flags + (g * 2 + q) * T_LEN;

  float cst[2][2] = {{0.f, 0.f}, {0.f, 0.f}};

  for (int st = 0; st < T_LEN; ++st) {
    const int t = dir ? (T_LEN - 1 - st) : st;

    // ---- stage x (waves 0-3, one frag each) ----
    {
      const char* xstep = xzb + (long)t * 8192;
      if (w < 4) {
        const int kt = w >> 1, nt = w & 1;
        gll16(xstep + (long)(((32 * q + nt * 16 + ln) * 64 + kt * 32 + lg * 8) * 2),
              zbuf + w * 1024);
      }
    }
    WAITV0;            // own gll16 (+ prior out-stores) done
    __syncthreads();   // (A) x staged

    // ---- acc init + x-projection (kt0,1) during the poll window ----
    f32x4 acc[2][2];
#pragma unroll
    for (int mtid = 0; mtid < 2; ++mtid)
#pragma unroll
      for (int nt = 0; nt < 2; ++nt) acc[mtid][nt] = biasv[mtid];
#pragma unroll
    for (int kt = 0; kt < 2; ++kt)
#pragma unroll
      for (int nt = 0; nt < 2; ++nt) {
        bf16x8 b = *reinterpret_cast<const bf16x8*>(
            zbuf + (kt * 2 + nt) * 1024 + l * 16);
        acc[0][nt] = __builtin_amdgcn_mfma_f32_16x16x32_bf16(W[0][kt], b, acc[0][nt], 0, 0, 0);
        acc[1][nt] = __builtin_amdgcn_mfma_f32_16x16x32_bf16(W[1][kt], b, acc[1][nt], 0, 0, 0);
      }

    // ---- poll partners' h(st-1) (R13 protocol verbatim) ----
    if (st > 0) {
      while (__hip_atomic_load(flg + (st - 1), __ATOMIC_RELAXED,
                               __HIP_MEMORY_SCOPE_AGENT) < 4)
        __builtin_amdgcn_s_sleep(2);
    }

    // ---- h reads: 2 frags/wave (f = 4+2w+j; kt = f>>1, nt = f&1) ----
    {
      bf16x8 hstg[2];
      if (st == 0) {
#pragma unroll
        for (int j = 0; j < 2; ++j) hstg[j] = (bf16x8)(short)0;
      } else {
        const char* hprev = hzg + (long)((st + 1) & 1) * 32768;
#pragma unroll
        for (int j = 0; j < 2; ++j) {
          const int f = 4 + 2 * w + j, kt = f >> 1, nt = f & 1;
          hstg[j] = ald16_dev(hprev +
              (long)(((32 * q + nt * 16 + ln) * 256 + (kt - 2) * 32 + lg * 8) * 2));
        }
      }
      WAITV0; SCHB;
#pragma unroll
      for (int j = 0; j < 2; ++j)
        *reinterpret_cast<bf16x8*>(zbuf + (4 + 2 * w + j) * 1024 + l * 16) = hstg[j];
    }
    __syncthreads();   // (B) h staged

    // ---- recurrent MFMA: kt2..9 x 2 nt x 2 mt ----
#pragma unroll
    for (int kt = 2; kt < 10; ++kt)
#pragma unroll
      for (int nt = 0; nt < 2; ++nt) {
        bf16x8 b = *reinterpret_cast<const bf16x8*>(
            zbuf + (kt * 2 + nt) * 1024 + l * 16);
        acc[0][nt] = __builtin_amdgcn_mfma_f32_16x16x32_bf16(W[0][kt], b, acc[0][nt], 0, 0, 0);
        acc[1][nt] = __builtin_amdgcn_mfma_f32_16x16x32_bf16(W[1][kt], b, acc[1][nt], 0, 0, 0);
      }

    // ---- epilogue (lane-local: regs 0..3 = gates i,f,g,o) ----
    float hv[2][2];
#pragma unroll
    for (int mtid = 0; mtid < 2; ++mtid)
#pragma unroll
      for (int nt = 0; nt < 2; ++nt) {
        float gi = sigmoidf_fast(acc[mtid][nt][0]);
        float gf = sigmoidf_fast(acc[mtid][nt][1]);
        float gg = tanhf_fast(acc[mtid][nt][2]);
        float go = sigmoidf_fast(acc[mtid][nt][3]);
        float cc = gf * cst[mtid][nt] + gi * gg;
        cst[mtid][nt] = cc;
        hv[mtid][nt] = go * tanhf_fast(cc);
      }
#pragma unroll
    for (int mtid = 0; mtid < 2; ++mtid)
#pragma unroll
      for (int nt = 0; nt < 2; ++nt)
        *reinterpret_cast<short*>(htr +
            (nt * 16 + ln) * 144 + (8 * w + 4 * mtid + lg) * 2) =
            f32_to_bf16(hv[mtid][nt]);
    __syncthreads();   // (C) htr complete

    // ---- publish h rectangle (sc0sc1; 4KB = 256 x 16B) ----
    {
      char* hcur = hzg + (long)(st & 1) * 32768;
      if (tid < 256) {
        const int a_l = tid >> 3, seg = tid & 7;
        bf16x8 v = *reinterpret_cast<const bf16x8*>(htr + a_l * 144 + seg * 16);
        ast16_dev(hcur + (long)(((32 * q + a_l) * 256 + 64 * p + seg * 8) * 2), v);
      }
    }
    WAITV0;            // publish at coherence point
    __syncthreads();   // (D) all waves drained; zbuf reads all done
    if (tid == 0)
      __hip_atomic_fetch_add(flg + st, 1, __ATOMIC_RELAXED,
                             __HIP_MEMORY_SCOPE_AGENT);

    // ---- out stores (after flag; overlap next step's poll) ----
    {
#pragma unroll
      for (int mtid = 0; mtid < 2; ++mtid)
#pragma unroll
        for (int nt = 0; nt < 2; ++nt) {
          const long u = 64 * p + 8 * w + 4 * mtid + lg;
          const int a = 32 * q + nt * 16 + ln;
          out[(((long)s * 512 + dir * 256 + u) * 128 + t) * 64 + a] = hv[mtid][nt];
        }
    }
  }
}

// ---------------- launcher ----------------
extern "C" void kernel_launch(void* const* d_in, const int* in_sizes, int n_in,
                              void* d_out, int out_size, void* d_ws, size_t ws_size,
                              hipStream_t stream) {
  const float* x     = (const float*)d_in[0];
  const float* Wih_f = (const float*)d_in[1];
  const float* Whh_f = (const float*)d_in[2];
  const float* bih_f = (const float*)d_in[3];
  const float* bhh_f = (const float*)d_in[4];
  const float* Wih_b = (const float*)d_in[5];
  const float* Whh_b = (const float*)d_in[6];
  const float* bih_b = (const float*)d_in[7];
  const float* bhh_b = (const float*)d_in[8];
  float* out = (float*)d_out;

  char* ws = (char*)d_ws;
  short* wf    = (short*)(ws + WF_OFF);
  float* bpk   = (float*)(ws + BI_OFF);
  short* xz    = (short*)(ws + XZ_OFF);
  short* hz    = (short*)(ws + HZ_OFF);
  int*   flags = (int*)(ws + FL_OFF);

  hipLaunchKernelGGL(pack_w, dim3(320), dim3(256), 0, stream,
                     Wih_f, Whh_f, Wih_b, Whh_b, wf);
  hipLaunchKernelGGL(pack_bias, dim3(32), dim3(256), 0, stream,
                     bih_f, bhh_f, bih_b, bhh_b, bpk);
  hipLaunchKernelGGL(pack_x, dim3(4096), dim3(256), 0, stream, x, xz);
  // zero flags only (hz is write-before-read; st=0 stages literal zeros)
  hipMemsetAsync(ws + FL_OFF, 0, WS_END - FL_OFF, stream);
  hipLaunchKernelGGL(lstm_rec, dim3(256), dim3(512), 0, stream,
                     wf, bpk, xz, hz, flags, out);
}